// Round 5
// baseline (1584.305 us; speedup 1.0000x reference)
//
#include <hip/hip_runtime.h>
#include <hip/hip_bf16.h>

// TAGConv x2 GNN on MI355X. v5:
//  - channel-grouped propagation: 8 groups of 16ch, group cg pinned to XCD cg
//    (blockIdx.x & 7) -> gather working set (g_in+g_out+esrc_u16 ~ 4.8MB)
//    lives in the per-XCD L2 instead of L3.
//  - store ONLY g_k = dis*h_k in planes [hop][8][N][16] fp16; GEMM recovers
//    h_k via per-row scale rs = sqrt(deg) in the epilogue. plane0 = s*x
//    (s = deg>0 ? dis : 1) so the W0 term survives deg-0 rows.
//  - esrc stored as u16 (N < 65536).
//  - GEMM: f16 MFMA, A fp16 (row-major or cg-plane layout), B split
//    (hi + lo*1024 fp16 planes, 2 MFMAs/step), fused epilogues.

#define EPS_MSG 1e-7f
#define BNSCALE 0.9999950000374997f  // 1/sqrt(1+1e-5)
#define LO_INV 0.0009765625f         // 2^-10

typedef _Float16 half_t;
typedef _Float16 f16x8 __attribute__((ext_vector_type(8)));
typedef float f32x4 __attribute__((ext_vector_type(4)));

// ---------------- CSR build ----------------

__global__ void zero_i32(int* __restrict__ p, int n) {
    int i = blockIdx.x * blockDim.x + threadIdx.x;
    if (i < n) p[i] = 0;
}

__global__ void count_deg(const int* __restrict__ col, int* __restrict__ deg, int E) {
    int e = blockIdx.x * blockDim.x + threadIdx.x;
    if (e < E) atomicAdd(&deg[col[e]], 1);
}

// dis = rsqrt(deg) (0 if deg==0); s = deg>0?dis:1; rs = deg>0?sqrt(deg):1
__global__ void compute_dis_s(const int* __restrict__ deg, float* __restrict__ dis,
                              float* __restrict__ s, float* __restrict__ rs, int N) {
    int v = blockIdx.x * blockDim.x + threadIdx.x;
    if (v >= N) return;
    int d = deg[v];
    float di = (d > 0) ? rsqrtf((float)d) : 0.f;
    dis[v] = di;
    s[v] = (d > 0) ? di : 1.f;
    rs[v] = (d > 0) ? sqrtf((float)d) : 1.f;
}

__global__ void scan_blk(const int* __restrict__ deg, int* __restrict__ off,
                         int* __restrict__ bsum, int N) {
    __shared__ int sm[1024];
    int i = blockIdx.x * 1024 + threadIdx.x;
    sm[threadIdx.x] = (i < N) ? deg[i] : 0;
    __syncthreads();
    for (int ofs = 1; ofs < 1024; ofs <<= 1) {
        int t = (threadIdx.x >= (unsigned)ofs) ? sm[threadIdx.x - ofs] : 0;
        __syncthreads();
        sm[threadIdx.x] += t;
        __syncthreads();
    }
    if (i < N) off[i + 1] = sm[threadIdx.x];
    if (threadIdx.x == 0) bsum[blockIdx.x] = sm[1023];
}

__global__ void scan_top(int* __restrict__ bsum, int nb) {
    if (threadIdx.x == 0 && blockIdx.x == 0) {
        int a = 0;
        for (int b = 0; b < nb; ++b) {
            int t = bsum[b];
            bsum[b] = a;
            a += t;
        }
    }
}

__global__ void scan_add(int* __restrict__ off, const int* __restrict__ bsum, int N) {
    int i = blockIdx.x * 1024 + threadIdx.x;
    if (i < N) off[i + 1] += bsum[blockIdx.x];
    if (i == 0) off[0] = 0;
}

__global__ void fill_edges(const int* __restrict__ row, const int* __restrict__ col,
                           const int* __restrict__ off, int* __restrict__ cur,
                           unsigned short* __restrict__ esrc, int E) {
    int e = blockIdx.x * blockDim.x + threadIdx.x;
    if (e >= E) return;
    int c = col[e];
    int pos = off[c] + atomicAdd(&cur[c], 1);
    esrc[pos] = (unsigned short)row[e];
}

// ---------------- conversions ----------------

// plane0[cg][v][16] = fp16(s*x); g0[cg][v][16] = fp16(dis*relu(x))
__global__ void conv_xg(const float* __restrict__ x, half_t* __restrict__ plane0,
                        half_t* __restrict__ g0, const float* __restrict__ dis,
                        const float* __restrict__ s, int N, int total) {
    int i = blockIdx.x * blockDim.x + threadIdx.x;
    if (i >= total) return;
    int v = i >> 7, ch = i & 127;
    int cg = ch >> 4, cc = ch & 15;
    float xv = x[i];
    size_t a = ((size_t)cg * N + v) * 16 + cc;
    plane0[a] = (half_t)(s[v] * xv);
    g0[a] = (half_t)(dis[v] * fmaxf(xv, 0.f));
}

// B^T planes: oh[n][km*K+k] = fp16(w), ol = fp16((w - fp16(w)) * 1024)
__global__ void conv_wt2(const float* __restrict__ in, half_t* __restrict__ oh,
                         half_t* __restrict__ ol, int nmats, int K, int Nn) {
    int total = nmats * K * Nn;
    int i = blockIdx.x * blockDim.x + threadIdx.x;
    if (i >= total) return;
    int KT = nmats * K;
    int n = i / KT;
    int rem = i - n * KT;
    int km = rem / K, k = rem - km * K;
    float w = in[(size_t)km * K * Nn + (size_t)k * Nn + n];
    half_t h = (half_t)w;
    oh[i] = h;
    ol[i] = (half_t)((w - (float)h) * 1024.f);
}

// ---------------- propagation (channel-grouped, XCD-local) ----------------
// gout[cg][v][c] = dis_v * (dis_v * sum_{in(v)} gin[cg][src][c] + indeg_v*EPS)

__global__ void __launch_bounds__(256) prop(const half_t* __restrict__ gin,
                                            half_t* __restrict__ gout,
                                            const float* __restrict__ dis,
                                            const int* __restrict__ off,
                                            const unsigned short* __restrict__ esrc,
                                            int N, int NB) {
    const int cg = blockIdx.x & 7;       // XCD-pinned channel group
    const int chunk = blockIdx.x >> 3;
    const int c = threadIdx.x & 15;
    const int el = (threadIdx.x >> 4) & 3;
    const int wv = threadIdx.x >> 6;
    const half_t* __restrict__ gb = gin + (size_t)cg * N * 16;
    half_t* __restrict__ ob = gout + (size_t)cg * N * 16;
    const int stride = NB * 4;
    for (int v = chunk * 4 + wv; v < N; v += stride) {
        int s = off[v], e = off[v + 1];
        float a0 = 0.f, a1 = 0.f;
        int i = s + el;
        for (; i + 4 < e; i += 8) {
            int s0 = esrc[i];
            int s1 = esrc[i + 4];
            a0 += (float)gb[(size_t)s0 * 16 + c];
            a1 += (float)gb[(size_t)s1 * 16 + c];
        }
        if (i < e) a0 += (float)gb[(size_t)esrc[i] * 16 + c];
        float a = a0 + a1;
        a += __shfl_xor(a, 16);
        a += __shfl_xor(a, 32);
        if (el == 0) {
            float dv = dis[v];
            float h = dv * a + (float)(e - s) * EPS_MSG;
            ob[(size_t)v * 16 + c] = (half_t)(dv * h);
        }
    }
}

// ---------------- f16 MFMA GEMM ----------------
// C[M,Ntot](ldc) = rs .* (A[M,Ktot] @ (Bh + Bl/1024)[Ntot][ldb]^T), fused epi.
// CGA: A in cg-plane layout [k/16][M][16]; else row-major lda=Ktot.
// epi: 1=+bias 2=relu(bn(v+bias)) 3=relu(v+bias)
// optional goutP = fp16(s*v), goutG = fp16(dis*v) in cg layout.

template <int BN, int CGA, int OUTF32>
__global__ __launch_bounds__(256) void gemmf16(
    int M, int Ktot, int Ntot, int ldc, int ldb,
    const half_t* __restrict__ A, const half_t* __restrict__ Bhp,
    const half_t* __restrict__ Blp, void* __restrict__ Cp,
    const float* __restrict__ rs, int epi, const float* __restrict__ bias,
    const float* __restrict__ bng, const float* __restrict__ bnb,
    half_t* __restrict__ goutP, const float* __restrict__ sArr,
    half_t* __restrict__ goutG, const float* __restrict__ disArr) {
    constexpr int BM = 64, BK = 32, PAD = 40;
    constexpr int WC = (BN == 128) ? 2 : 1;
    constexpr int WR = 4 / WC;
    constexpr int WROWS = BM / WR;
    constexpr int WCOLS = BN / WC;  // 64
    constexpr int MF = WROWS / 16;
    constexpr int NF = WCOLS / 16;
    constexpr int BIT = (BN * BK) / (256 * 8);

    __shared__ half_t Ah[BM][PAD];
    __shared__ half_t Bh[BN][PAD];
    __shared__ half_t Bl[BN][PAD];

    const int tid = threadIdx.x;
    const int lane = tid & 63;
    const int w = tid >> 6;
    const int wr = w / WC, wc = w % WC;
    const int m0 = blockIdx.x * BM;
    const int n0 = blockIdx.y * BN;

    uint4 ra, rbh[BIT], rbl[BIT];

    auto stage_load = [&](int k0) {
        {
            int f = tid * 8;
            int r = f >> 5, kk = f & 31;
            int gv = m0 + r;
            const half_t* src;
            if (CGA)
                src = &A[((size_t)((k0 + kk) >> 4) * M + gv) * 16 + (kk & 15)];
            else
                src = &A[(size_t)gv * Ktot + k0 + kk];
            ra = (gv < M) ? *reinterpret_cast<const uint4*>(src) : make_uint4(0u, 0u, 0u, 0u);
        }
#pragma unroll
        for (int it = 0; it < BIT; ++it) {
            int f = (tid + it * 256) * 8;
            int r = f >> 5, kk = f & 31;
            rbh[it] = *reinterpret_cast<const uint4*>(&Bhp[(size_t)(n0 + r) * ldb + k0 + kk]);
            rbl[it] = *reinterpret_cast<const uint4*>(&Blp[(size_t)(n0 + r) * ldb + k0 + kk]);
        }
    };
    auto stage_write = [&]() {
        {
            int f = tid * 8;
            int r = f >> 5, kk = f & 31;
            *reinterpret_cast<uint4*>(&Ah[r][kk]) = ra;
        }
#pragma unroll
        for (int it = 0; it < BIT; ++it) {
            int f = (tid + it * 256) * 8;
            int r = f >> 5, kk = f & 31;
            *reinterpret_cast<uint4*>(&Bh[r][kk]) = rbh[it];
            *reinterpret_cast<uint4*>(&Bl[r][kk]) = rbl[it];
        }
    };

    f32x4 acch[MF][NF], accl[MF][NF];
#pragma unroll
    for (int fm = 0; fm < MF; ++fm)
#pragma unroll
        for (int fn = 0; fn < NF; ++fn) {
            acch[fm][fn] = (f32x4){0.f, 0.f, 0.f, 0.f};
            accl[fm][fn] = (f32x4){0.f, 0.f, 0.f, 0.f};
        }

    stage_load(0);
    const int kiters = Ktot / BK;
    for (int ki = 0; ki < kiters; ++ki) {
        stage_write();
        __syncthreads();
        if (ki + 1 < kiters) stage_load((ki + 1) * BK);

        const int koff = (lane >> 4) * 8;
        f16x8 af[MF];
#pragma unroll
        for (int fm = 0; fm < MF; ++fm) {
            int rowb = wr * WROWS + fm * 16 + (lane & 15);
            af[fm] = *reinterpret_cast<const f16x8*>(&Ah[rowb][koff]);
        }
#pragma unroll
        for (int fn = 0; fn < NF; ++fn) {
            int colb = wc * WCOLS + fn * 16 + (lane & 15);
            f16x8 bh = *reinterpret_cast<const f16x8*>(&Bh[colb][koff]);
            f16x8 bl = *reinterpret_cast<const f16x8*>(&Bl[colb][koff]);
#pragma unroll
            for (int fm = 0; fm < MF; ++fm) {
                acch[fm][fn] =
                    __builtin_amdgcn_mfma_f32_16x16x32_f16(af[fm], bh, acch[fm][fn], 0, 0, 0);
                accl[fm][fn] =
                    __builtin_amdgcn_mfma_f32_16x16x32_f16(af[fm], bl, accl[fm][fn], 0, 0, 0);
            }
        }
        __syncthreads();
    }

    // C/D layout: col = lane&15, row = (lane>>4)*4 + i
#pragma unroll
    for (int fm = 0; fm < MF; ++fm) {
#pragma unroll
        for (int fn = 0; fn < NF; ++fn) {
#pragma unroll
            for (int i = 0; i < 4; ++i) {
                int gr = m0 + wr * WROWS + fm * 16 + (lane >> 4) * 4 + i;
                if (gr >= M) continue;
                int gc = n0 + wc * WCOLS + fn * 16 + (lane & 15);
                float v = acch[fm][fn][i] + accl[fm][fn][i] * LO_INV;
                if (rs) v *= rs[gr];
                if (epi == 1) {
                    v += bias[gc];
                } else if (epi == 2) {
                    v = bng[gc] * ((v + bias[gc]) * BNSCALE) + bnb[gc];
                    v = fmaxf(v, 0.f);
                } else if (epi == 3) {
                    v = fmaxf(v + bias[gc], 0.f);
                }
                if (Cp) {
                    if (OUTF32)
                        ((float*)Cp)[(size_t)gr * ldc + gc] = v;
                    else
                        ((half_t*)Cp)[(size_t)gr * ldc + gc] = (half_t)v;
                }
                if (goutP) {
                    size_t a = ((size_t)(gc >> 4) * M + gr) * 16 + (gc & 15);
                    goutP[a] = (half_t)(sArr[gr] * v);
                    goutG[a] = (half_t)(disArr[gr] * v);
                }
            }
        }
    }
}

extern "C" void kernel_launch(void* const* d_in, const int* in_sizes, int n_in,
                              void* d_out, int out_size, void* d_ws, size_t ws_size,
                              hipStream_t stream) {
    const float* x     = (const float*)d_in[0];
    const int*   ei    = (const int*)d_in[1];
    const float* lins1 = (const float*)d_in[2];
    const float* bias1 = (const float*)d_in[3];
    const float* m1w1  = (const float*)d_in[4];
    const float* m1b1  = (const float*)d_in[5];
    const float* bn1g  = (const float*)d_in[6];
    const float* bn1b  = (const float*)d_in[7];
    const float* m1w2  = (const float*)d_in[8];
    const float* m1b2  = (const float*)d_in[9];
    const float* lins2 = (const float*)d_in[10];
    const float* bias2 = (const float*)d_in[11];
    const float* m2w1  = (const float*)d_in[12];
    const float* m2b1  = (const float*)d_in[13];
    const float* bn2g  = (const float*)d_in[14];
    const float* bn2b  = (const float*)d_in[15];
    const float* m2w2  = (const float*)d_in[16];
    const float* m2b2  = (const float*)d_in[17];
    float* out = (float*)d_out;

    const int N = in_sizes[0] / 128;
    const int E = in_sizes[1] / 2;
    const int* row = ei;
    const int* col = ei + E;

    char* ws = (char*)d_ws;
    size_t o = 0;
    auto alloc = [&](size_t bytes) {
        void* p = ws + o;
        o += (bytes + 255) & ~(size_t)255;
        return p;
    };
    int*            deg  = (int*)alloc((size_t)N * 4);
    int*            cur  = (int*)alloc((size_t)N * 4);
    float*          dis  = (float*)alloc((size_t)N * 4);
    float*          sA   = (float*)alloc((size_t)N * 4);
    float*          rsA  = (float*)alloc((size_t)N * 4);
    int*            off  = (int*)alloc((size_t)(N + 1) * 4);
    int*            bsum = (int*)alloc(1024 * 4);
    unsigned short* esrc = (unsigned short*)alloc((size_t)E * 2);
    // planes[hop][cg][N][16] fp16: hop 0..6; reused by both layers
    half_t* planes = (half_t*)alloc((size_t)7 * 8 * N * 16 * 2);
    half_t* g0     = (half_t*)alloc((size_t)8 * N * 16 * 2);
    half_t* ACC    = (half_t*)alloc((size_t)N * 128 * 2);
    half_t* Z      = (half_t*)alloc((size_t)N * 256 * 2);
    half_t* ACC2   = (half_t*)alloc((size_t)N * 64 * 2);
    half_t* Wc1h   = (half_t*)alloc((size_t)128 * 896 * 2);
    half_t* Wc1l   = (half_t*)alloc((size_t)128 * 896 * 2);
    half_t* Wc2h   = (half_t*)alloc((size_t)64 * 896 * 2);
    half_t* Wc2l   = (half_t*)alloc((size_t)64 * 896 * 2);
    half_t* Wm1ah  = (half_t*)alloc((size_t)256 * 128 * 2);
    half_t* Wm1al  = (half_t*)alloc((size_t)256 * 128 * 2);
    half_t* Wm1bh  = (half_t*)alloc((size_t)128 * 256 * 2);
    half_t* Wm1bl  = (half_t*)alloc((size_t)128 * 256 * 2);
    half_t* Wm2ah  = (half_t*)alloc((size_t)128 * 64 * 2);
    half_t* Wm2al  = (half_t*)alloc((size_t)128 * 64 * 2);
    half_t* Wm2bh  = (half_t*)alloc((size_t)64 * 128 * 2);
    half_t* Wm2bl  = (half_t*)alloc((size_t)64 * 128 * 2);
    (void)ws_size;

    const size_t PL = (size_t)8 * N * 16;  // elements per hop-plane
    half_t* Z2 = Z;                        // [N,128], Z dead by then

    const int TPB = 256;
    const int nb = (N + 1023) / 1024;
    zero_i32<<<(N + TPB - 1) / TPB, TPB, 0, stream>>>(deg, N);
    zero_i32<<<(N + TPB - 1) / TPB, TPB, 0, stream>>>(cur, N);
    count_deg<<<(E + TPB - 1) / TPB, TPB, 0, stream>>>(col, deg, E);
    compute_dis_s<<<(N + TPB - 1) / TPB, TPB, 0, stream>>>(deg, dis, sA, rsA, N);
    scan_blk<<<nb, 1024, 0, stream>>>(deg, off, bsum, N);
    scan_top<<<1, 64, 0, stream>>>(bsum, nb);
    scan_add<<<nb, 1024, 0, stream>>>(off, bsum, N);
    fill_edges<<<(E + TPB - 1) / TPB, TPB, 0, stream>>>(row, col, off, cur, esrc, E);

    conv_wt2<<<(7 * 128 * 128 + TPB - 1) / TPB, TPB, 0, stream>>>(lins1, Wc1h, Wc1l, 7, 128, 128);
    conv_wt2<<<(7 * 128 * 64 + TPB - 1) / TPB, TPB, 0, stream>>>(lins2, Wc2h, Wc2l, 7, 128, 64);
    conv_wt2<<<(128 * 256 + TPB - 1) / TPB, TPB, 0, stream>>>(m1w1, Wm1ah, Wm1al, 1, 128, 256);
    conv_wt2<<<(256 * 128 + TPB - 1) / TPB, TPB, 0, stream>>>(m1w2, Wm1bh, Wm1bl, 1, 256, 128);
    conv_wt2<<<(64 * 128 + TPB - 1) / TPB, TPB, 0, stream>>>(m2w1, Wm2ah, Wm2al, 1, 64, 128);
    conv_wt2<<<(128 * 64 + TPB - 1) / TPB, TPB, 0, stream>>>(m2w2, Wm2bh, Wm2bl, 1, 128, 64);

    conv_xg<<<(N * 128 + TPB - 1) / TPB, TPB, 0, stream>>>(x, planes, g0, dis, sA, N, N * 128);

    const int PGRID = 2048, PNB = PGRID / 8;
    const int HG = (N + 63) / 64;

    // ---- Layer 1: 6 hops then one K=896 concat GEMM ----
    for (int k = 1; k <= 6; ++k) {
        const half_t* gin = (k == 1) ? g0 : planes + (size_t)(k - 1) * PL;
        prop<<<PGRID, 256, 0, stream>>>(gin, planes + (size_t)k * PL, dis, off, esrc, N, PNB);
    }
    {
        dim3 grid(HG, 1);
        gemmf16<128, 1, 0><<<grid, 256, 0, stream>>>(N, 896, 128, 128, 896, planes, Wc1h, Wc1l,
                                                     ACC, rsA, 1, bias1, nullptr, nullptr,
                                                     nullptr, nullptr, nullptr, nullptr);
    }
    // ---- MLP1: Z = relu(bn(ACC@W+b)); h1 = relu(Z@W+b) -> plane0 (s*h1), g0 (dis*h1) ----
    {
        dim3 grid(HG, 2);
        gemmf16<128, 0, 0><<<grid, 256, 0, stream>>>(N, 128, 256, 256, 128, ACC, Wm1ah, Wm1al, Z,
                                                     nullptr, 2, m1b1, bn1g, bn1b, nullptr,
                                                     nullptr, nullptr, nullptr);
    }
    {
        dim3 grid(HG, 1);
        gemmf16<128, 0, 0><<<grid, 256, 0, stream>>>(N, 256, 128, 0, 256, Z, Wm1bh, Wm1bl,
                                                     nullptr, nullptr, 3, m1b2, nullptr, nullptr,
                                                     planes, sA, g0, dis);
    }
    // ---- Layer 2: 6 hops then one K=896 concat GEMM (Ntot=64) ----
    for (int k = 1; k <= 6; ++k) {
        const half_t* gin = (k == 1) ? g0 : planes + (size_t)(k - 1) * PL;
        prop<<<PGRID, 256, 0, stream>>>(gin, planes + (size_t)k * PL, dis, off, esrc, N, PNB);
    }
    {
        dim3 grid(HG, 1);
        gemmf16<64, 1, 0><<<grid, 256, 0, stream>>>(N, 896, 64, 64, 896, planes, Wc2h, Wc2l,
                                                    ACC2, rsA, 1, bias2, nullptr, nullptr,
                                                    nullptr, nullptr, nullptr, nullptr);
    }
    // ---- MLP2 ----
    {
        dim3 grid(HG, 1);
        gemmf16<128, 0, 0><<<grid, 256, 0, stream>>>(N, 64, 128, 128, 64, ACC2, Wm2ah, Wm2al, Z2,
                                                     nullptr, 2, m2b1, bn2g, bn2b, nullptr,
                                                     nullptr, nullptr, nullptr);
    }
    {
        dim3 grid(HG, 1);
        gemmf16<64, 0, 1><<<grid, 256, 0, stream>>>(N, 128, 64, 64, 128, Z2, Wm2bh, Wm2bl, out,
                                                    nullptr, 1, m2b2, nullptr, nullptr, nullptr,
                                                    nullptr, nullptr, nullptr);
    }
}

// Round 6
// 949.580 us; speedup vs baseline: 1.6684x; 1.6684x over previous
//
#include <hip/hip_runtime.h>
#include <hip/hip_bf16.h>

// TAGConv x2 GNN on MI355X. v6:
//  - G-slab [N][896] fp16 holds dis*h_k per hop col-block; GEMM epilogue
//    recovers h_k via rs=sqrt(deg) row scale (plane0 = s*x, s=deg>0?dis:1).
//  - prop: wave-per-node, lane=u32 (2ch) -> one fully-used 256B request per
//    edge per wave; predicated 8-wide edge loop -> 8 outstanding gathers.
//  - GEMM: f16 MFMA, BK=64, A-prefetch depth 2 (B issued first so vmcnt
//    leaves A in flight), B split hi + lo*1024, template-unrolled K loop.

#define EPS_MSG 1e-7f
#define BNSCALE 0.9999950000374997f  // 1/sqrt(1+1e-5)
#define LO_INV 0.0009765625f         // 2^-10

typedef _Float16 half_t;
typedef _Float16 f16x8 __attribute__((ext_vector_type(8)));
typedef float f32x4 __attribute__((ext_vector_type(4)));

__device__ __forceinline__ float hlo(unsigned p) {
    unsigned short u = (unsigned short)(p & 0xffffu);
    half_t h;
    __builtin_memcpy(&h, &u, 2);
    return (float)h;
}
__device__ __forceinline__ float hhi(unsigned p) {
    unsigned short u = (unsigned short)(p >> 16);
    half_t h;
    __builtin_memcpy(&h, &u, 2);
    return (float)h;
}
__device__ __forceinline__ unsigned fpack2(float x, float y) {
    half_t a = (half_t)x, b = (half_t)y;
    unsigned short ua, ub;
    __builtin_memcpy(&ua, &a, 2);
    __builtin_memcpy(&ub, &b, 2);
    return (unsigned)ua | ((unsigned)ub << 16);
}

// ---------------- CSR build ----------------

__global__ void zero_i32(int* __restrict__ p, int n) {
    int i = blockIdx.x * blockDim.x + threadIdx.x;
    if (i < n) p[i] = 0;
}

__global__ void count_deg(const int* __restrict__ col, int* __restrict__ deg, int E) {
    int e = blockIdx.x * blockDim.x + threadIdx.x;
    if (e < E) atomicAdd(&deg[col[e]], 1);
}

__global__ void compute_dis_s(const int* __restrict__ deg, float* __restrict__ dis,
                              float* __restrict__ s, float* __restrict__ rs, int N) {
    int v = blockIdx.x * blockDim.x + threadIdx.x;
    if (v >= N) return;
    int d = deg[v];
    float di = (d > 0) ? rsqrtf((float)d) : 0.f;
    dis[v] = di;
    s[v] = (d > 0) ? di : 1.f;
    rs[v] = (d > 0) ? sqrtf((float)d) : 1.f;
}

__global__ void scan_blk(const int* __restrict__ deg, int* __restrict__ off,
                         int* __restrict__ bsum, int N) {
    __shared__ int sm[1024];
    int i = blockIdx.x * 1024 + threadIdx.x;
    sm[threadIdx.x] = (i < N) ? deg[i] : 0;
    __syncthreads();
    for (int ofs = 1; ofs < 1024; ofs <<= 1) {
        int t = (threadIdx.x >= (unsigned)ofs) ? sm[threadIdx.x - ofs] : 0;
        __syncthreads();
        sm[threadIdx.x] += t;
        __syncthreads();
    }
    if (i < N) off[i + 1] = sm[threadIdx.x];
    if (threadIdx.x == 0) bsum[blockIdx.x] = sm[1023];
}

__global__ void scan_top(int* __restrict__ bsum, int nb) {
    if (threadIdx.x == 0 && blockIdx.x == 0) {
        int a = 0;
        for (int b = 0; b < nb; ++b) {
            int t = bsum[b];
            bsum[b] = a;
            a += t;
        }
    }
}

__global__ void scan_add(int* __restrict__ off, const int* __restrict__ bsum, int N) {
    int i = blockIdx.x * 1024 + threadIdx.x;
    if (i < N) off[i + 1] += bsum[blockIdx.x];
    if (i == 0) off[0] = 0;
}

__global__ void fill_edges(const int* __restrict__ row, const int* __restrict__ col,
                           const int* __restrict__ off, int* __restrict__ cur,
                           unsigned short* __restrict__ esrc, int E) {
    int e = blockIdx.x * blockDim.x + threadIdx.x;
    if (e >= E) return;
    int c = col[e];
    int pos = off[c] + atomicAdd(&cur[c], 1);
    esrc[pos] = (unsigned short)row[e];
}

// ---------------- conversions ----------------

// slab col0 = fp16(s*x) (stride 896); g0 = fp16(dis*relu(x))
__global__ void conv_xg(const float* __restrict__ x, half_t* __restrict__ slab,
                        half_t* __restrict__ g0, const float* __restrict__ dis,
                        const float* __restrict__ s, int total) {
    int i = blockIdx.x * blockDim.x + threadIdx.x;
    if (i >= total) return;
    int v = i >> 7, c = i & 127;
    float xv = x[i];
    slab[(size_t)v * 896 + c] = (half_t)(s[v] * xv);
    g0[i] = (half_t)(dis[v] * fmaxf(xv, 0.f));
}

__device__ __forceinline__ void wcv(const float* __restrict__ in, half_t* __restrict__ oh,
                                    half_t* __restrict__ ol, int nm, int K, int Nn, int i) {
    int KT = nm * K;
    int n = i / KT;
    int rem = i - n * KT;
    int km = rem / K, k = rem - km * K;
    float w = in[(size_t)km * K * Nn + (size_t)k * Nn + n];
    half_t h = (half_t)w;
    oh[i] = h;
    ol[i] = (half_t)((w - (float)h) * 1024.f);
}

// all six weight matrices -> B^T hi/lo fp16 planes, one kernel
__global__ void conv_all(const float* l1, const float* l2, const float* a1, const float* b1,
                         const float* a2, const float* b2, half_t* W1h, half_t* W1l,
                         half_t* W2h, half_t* W2l, half_t* M1ah, half_t* M1al, half_t* M1bh,
                         half_t* M1bl, half_t* M2ah, half_t* M2al, half_t* M2bh,
                         half_t* M2bl) {
    int i = blockIdx.x * blockDim.x + threadIdx.x;
    if (i < 114688) {
        wcv(l1, W1h, W1l, 7, 128, 128, i);
    } else if (i < 172032) {
        wcv(l2, W2h, W2l, 7, 128, 64, i - 114688);
    } else if (i < 204800) {
        wcv(a1, M1ah, M1al, 1, 128, 256, i - 172032);
    } else if (i < 237568) {
        wcv(b1, M1bh, M1bl, 1, 256, 128, i - 204800);
    } else if (i < 245760) {
        wcv(a2, M2ah, M2al, 1, 64, 128, i - 237568);
    } else if (i < 253952) {
        wcv(b2, M2bh, M2bl, 1, 128, 64, i - 245760);
    }
}

// ---------------- propagation ----------------
// gout[v] = dis_v * (dis_v * sum_{in(v)} gin[src] + indeg_v*EPS)   (per 2ch/lane)

__global__ void __launch_bounds__(256) prop(const unsigned* __restrict__ gin, int idl,
                                            unsigned* __restrict__ gout, int odl,
                                            const float* __restrict__ dis,
                                            const int* __restrict__ off,
                                            const unsigned short* __restrict__ esrc, int N) {
    const int lane = threadIdx.x & 63;
    const int w = threadIdx.x >> 6;
    const int stride = gridDim.x * 4;
    for (int v = blockIdx.x * 4 + w; v < N; v += stride) {
        int s = off[v], e = off[v + 1];
        float2 A0 = {0.f, 0.f}, A1 = {0.f, 0.f}, A2 = {0.f, 0.f}, A3 = {0.f, 0.f};
        float2 A4 = {0.f, 0.f}, A5 = {0.f, 0.f}, A6 = {0.f, 0.f}, A7 = {0.f, 0.f};
        for (int i = s; i < e; i += 8) {
            unsigned p[8];
            int ok[8];
#pragma unroll
            for (int j = 0; j < 8; ++j) {
                int ij = i + j;
                ok[j] = ij < e;
                int idx = ok[j] ? ij : e - 1;
                p[j] = gin[esrc[idx] * idl + lane];
            }
            A0.x += ok[0] ? hlo(p[0]) : 0.f; A0.y += ok[0] ? hhi(p[0]) : 0.f;
            A1.x += ok[1] ? hlo(p[1]) : 0.f; A1.y += ok[1] ? hhi(p[1]) : 0.f;
            A2.x += ok[2] ? hlo(p[2]) : 0.f; A2.y += ok[2] ? hhi(p[2]) : 0.f;
            A3.x += ok[3] ? hlo(p[3]) : 0.f; A3.y += ok[3] ? hhi(p[3]) : 0.f;
            A4.x += ok[4] ? hlo(p[4]) : 0.f; A4.y += ok[4] ? hhi(p[4]) : 0.f;
            A5.x += ok[5] ? hlo(p[5]) : 0.f; A5.y += ok[5] ? hhi(p[5]) : 0.f;
            A6.x += ok[6] ? hlo(p[6]) : 0.f; A6.y += ok[6] ? hhi(p[6]) : 0.f;
            A7.x += ok[7] ? hlo(p[7]) : 0.f; A7.y += ok[7] ? hhi(p[7]) : 0.f;
        }
        float ax = ((A0.x + A1.x) + (A2.x + A3.x)) + ((A4.x + A5.x) + (A6.x + A7.x));
        float ay = ((A0.y + A1.y) + (A2.y + A3.y)) + ((A4.y + A5.y) + (A6.y + A7.y));
        float dv = dis[v];
        float ce = (float)(e - s) * EPS_MSG;
        float hx = fmaf(dv, ax, ce);
        float hy = fmaf(dv, ay, ce);
        gout[v * odl + lane] = fpack2(dv * hx, dv * hy);
    }
}

// ---------------- f16 MFMA GEMM ----------------
// C[M,*](ldc) = epi( rs .* (A[M,K] @ (Bh + Bl/1024)^T) )
// epi: 1=+bias 2=relu(bn(v+bias)) 3=relu(v+bias)
// optional strided goutP = s*v, goutG = dis*v.

template <int BN, int KITERS, int OUTF32>
__global__ __launch_bounds__(256) void gemm(
    int M, const half_t* __restrict__ A, int lda, const half_t* __restrict__ Bhp,
    const half_t* __restrict__ Blp, int ldb, void* __restrict__ Cp, int ldc,
    const float* __restrict__ rs, int epi, const float* __restrict__ bias,
    const float* __restrict__ bng, const float* __restrict__ bnb,
    half_t* __restrict__ goutP, int ldp, const float* __restrict__ sArr,
    half_t* __restrict__ goutG, int ldg, const float* __restrict__ disArr) {
    constexpr int BM = 64, BK = 64, PADE = 72;  // 144B rows: odd x16B
    constexpr int WC = (BN == 128) ? 2 : 1;
    constexpr int WROWS = BM / (4 / WC);  // 32 or 16
    constexpr int WCOLS = 64;
    constexpr int MF = WROWS / 16;
    constexpr int NF = 4;
    constexpr int AIT = 2;
    constexpr int BIT = (BN * BK) / (256 * 8);  // 4 or 2

    __shared__ half_t Ahs[BM][PADE];
    __shared__ half_t Bhs[BN][PADE];
    __shared__ half_t Bls[BN][PADE];

    const int tid = threadIdx.x;
    const int lane = tid & 63;
    const int w = tid >> 6;
    const int wr = w / WC, wc = w % WC;
    const int m0 = blockIdx.x * BM;
    const int n0 = blockIdx.y * BN;

    uint4 ra0[AIT], ra1[AIT], rbh[BIT], rbl[BIT];

    auto loadA = [&](uint4(&dst)[AIT], int k0) {
#pragma unroll
        for (int it = 0; it < AIT; ++it) {
            int f = (tid + it * 256) * 8;
            int r = f >> 6, kk = f & 63;
            int gv = m0 + r;
            dst[it] = (gv < M)
                          ? *reinterpret_cast<const uint4*>(&A[(size_t)gv * lda + k0 + kk])
                          : make_uint4(0u, 0u, 0u, 0u);
        }
    };
    auto loadB = [&](int k0) {
#pragma unroll
        for (int it = 0; it < BIT; ++it) {
            int f = (tid + it * 256) * 8;
            int r = f >> 6, kk = f & 63;
            rbh[it] = *reinterpret_cast<const uint4*>(&Bhp[(size_t)(n0 + r) * ldb + k0 + kk]);
            rbl[it] = *reinterpret_cast<const uint4*>(&Blp[(size_t)(n0 + r) * ldb + k0 + kk]);
        }
    };
    auto writeA = [&](uint4(&src)[AIT]) {
#pragma unroll
        for (int it = 0; it < AIT; ++it) {
            int f = (tid + it * 256) * 8;
            int r = f >> 6, kk = f & 63;
            *reinterpret_cast<uint4*>(&Ahs[r][kk]) = src[it];
        }
    };
    auto writeB = [&]() {
#pragma unroll
        for (int it = 0; it < BIT; ++it) {
            int f = (tid + it * 256) * 8;
            int r = f >> 6, kk = f & 63;
            *reinterpret_cast<uint4*>(&Bhs[r][kk]) = rbh[it];
            *reinterpret_cast<uint4*>(&Bls[r][kk]) = rbl[it];
        }
    };

    f32x4 acch[MF][NF], accl[MF][NF];
#pragma unroll
    for (int fm = 0; fm < MF; ++fm)
#pragma unroll
        for (int fn = 0; fn < NF; ++fn) {
            acch[fm][fn] = (f32x4){0.f, 0.f, 0.f, 0.f};
            accl[fm][fn] = (f32x4){0.f, 0.f, 0.f, 0.f};
        }

    // prologue: B first, then A(0), A(1) -> waits on B leave A(1) in flight
    loadB(0);
    loadA(ra0, 0);
    if (KITERS > 1) loadA(ra1, BK);

#pragma unroll
    for (int ki = 0; ki < KITERS; ++ki) {
        if ((ki & 1) == 0)
            writeA(ra0);
        else
            writeA(ra1);
        writeB();
        __syncthreads();
        if (ki + 1 < KITERS) loadB((ki + 1) * BK);  // B before A: vmcnt keeps A deep
        if (ki + 2 < KITERS) {
            if ((ki & 1) == 0)
                loadA(ra0, (ki + 2) * BK);
            else
                loadA(ra1, (ki + 2) * BK);
        }
#pragma unroll
        for (int ks = 0; ks < 2; ++ks) {
            const int ko = ks * 32 + (lane >> 4) * 8;
            f16x8 af[MF];
#pragma unroll
            for (int fm = 0; fm < MF; ++fm)
                af[fm] =
                    *reinterpret_cast<const f16x8*>(&Ahs[wr * WROWS + fm * 16 + (lane & 15)][ko]);
#pragma unroll
            for (int fn = 0; fn < NF; ++fn) {
                const int colb = wc * WCOLS + fn * 16 + (lane & 15);
                f16x8 bhv = *reinterpret_cast<const f16x8*>(&Bhs[colb][ko]);
                f16x8 blv = *reinterpret_cast<const f16x8*>(&Bls[colb][ko]);
#pragma unroll
                for (int fm = 0; fm < MF; ++fm) {
                    acch[fm][fn] =
                        __builtin_amdgcn_mfma_f32_16x16x32_f16(af[fm], bhv, acch[fm][fn], 0, 0, 0);
                    accl[fm][fn] =
                        __builtin_amdgcn_mfma_f32_16x16x32_f16(af[fm], blv, accl[fm][fn], 0, 0, 0);
                }
            }
        }
        __syncthreads();
    }

    // C/D layout: col = lane&15, row = (lane>>4)*4 + i
#pragma unroll
    for (int fm = 0; fm < MF; ++fm)
#pragma unroll
        for (int fn = 0; fn < NF; ++fn)
#pragma unroll
            for (int i = 0; i < 4; ++i) {
                int gr = m0 + wr * WROWS + fm * 16 + (lane >> 4) * 4 + i;
                if (gr >= M) continue;
                int gc = n0 + wc * WCOLS + fn * 16 + (lane & 15);
                float v = acch[fm][fn][i] + accl[fm][fn][i] * LO_INV;
                if (rs) v *= rs[gr];
                if (epi == 1) {
                    v += bias[gc];
                } else if (epi == 2) {
                    v = bng[gc] * ((v + bias[gc]) * BNSCALE) + bnb[gc];
                    v = fmaxf(v, 0.f);
                } else if (epi == 3) {
                    v = fmaxf(v + bias[gc], 0.f);
                }
                if (Cp) {
                    if (OUTF32)
                        ((float*)Cp)[(size_t)gr * ldc + gc] = v;
                    else
                        ((half_t*)Cp)[(size_t)gr * ldc + gc] = (half_t)v;
                }
                if (goutP) goutP[(size_t)gr * ldp + gc] = (half_t)(sArr[gr] * v);
                if (goutG) goutG[(size_t)gr * ldg + gc] = (half_t)(disArr[gr] * v);
            }
}

extern "C" void kernel_launch(void* const* d_in, const int* in_sizes, int n_in,
                              void* d_out, int out_size, void* d_ws, size_t ws_size,
                              hipStream_t stream) {
    const float* x     = (const float*)d_in[0];
    const int*   ei    = (const int*)d_in[1];
    const float* lins1 = (const float*)d_in[2];
    const float* bias1 = (const float*)d_in[3];
    const float* m1w1  = (const float*)d_in[4];
    const float* m1b1  = (const float*)d_in[5];
    const float* bn1g  = (const float*)d_in[6];
    const float* bn1b  = (const float*)d_in[7];
    const float* m1w2  = (const float*)d_in[8];
    const float* m1b2  = (const float*)d_in[9];
    const float* lins2 = (const float*)d_in[10];
    const float* bias2 = (const float*)d_in[11];
    const float* m2w1  = (const float*)d_in[12];
    const float* m2b1  = (const float*)d_in[13];
    const float* bn2g  = (const float*)d_in[14];
    const float* bn2b  = (const float*)d_in[15];
    const float* m2w2  = (const float*)d_in[16];
    const float* m2b2  = (const float*)d_in[17];
    float* out = (float*)d_out;

    const int N = in_sizes[0] / 128;
    const int E = in_sizes[1] / 2;
    const int* row = ei;
    const int* col = ei + E;

    char* ws = (char*)d_ws;
    size_t o = 0;
    auto alloc = [&](size_t bytes) {
        void* p = ws + o;
        o += (bytes + 255) & ~(size_t)255;
        return p;
    };
    int*            deg  = (int*)alloc((size_t)N * 4);
    int*            cur  = (int*)alloc((size_t)N * 4);
    float*          dis  = (float*)alloc((size_t)N * 4);
    float*          sA   = (float*)alloc((size_t)N * 4);
    float*          rsA  = (float*)alloc((size_t)N * 4);
    int*            off  = (int*)alloc((size_t)(N + 1) * 4);
    int*            bsum = (int*)alloc(1024 * 4);
    unsigned short* esrc = (unsigned short*)alloc((size_t)E * 2);
    half_t* g0    = (half_t*)alloc((size_t)N * 128 * 2);
    half_t* ACC   = (half_t*)alloc((size_t)N * 128 * 2);
    half_t* Z     = (half_t*)alloc((size_t)N * 256 * 2);
    half_t* ACC2  = (half_t*)alloc((size_t)N * 64 * 2);
    half_t* Wc1h  = (half_t*)alloc((size_t)128 * 896 * 2);
    half_t* Wc1l  = (half_t*)alloc((size_t)128 * 896 * 2);
    half_t* Wc2h  = (half_t*)alloc((size_t)64 * 896 * 2);
    half_t* Wc2l  = (half_t*)alloc((size_t)64 * 896 * 2);
    half_t* Wm1ah = (half_t*)alloc((size_t)256 * 128 * 2);
    half_t* Wm1al = (half_t*)alloc((size_t)256 * 128 * 2);
    half_t* Wm1bh = (half_t*)alloc((size_t)128 * 256 * 2);
    half_t* Wm1bl = (half_t*)alloc((size_t)128 * 256 * 2);
    half_t* Wm2ah = (half_t*)alloc((size_t)128 * 64 * 2);
    half_t* Wm2al = (half_t*)alloc((size_t)128 * 64 * 2);
    half_t* Wm2bh = (half_t*)alloc((size_t)64 * 128 * 2);
    half_t* Wm2bl = (half_t*)alloc((size_t)64 * 128 * 2);
    half_t* slab  = (half_t*)alloc((size_t)N * 896 * 2);
    (void)ws_size;

    const int TPB = 256;
    const int nb = (N + 1023) / 1024;
    zero_i32<<<(N + TPB - 1) / TPB, TPB, 0, stream>>>(deg, N);
    zero_i32<<<(N + TPB - 1) / TPB, TPB, 0, stream>>>(cur, N);
    count_deg<<<(E + TPB - 1) / TPB, TPB, 0, stream>>>(col, deg, E);
    compute_dis_s<<<(N + TPB - 1) / TPB, TPB, 0, stream>>>(deg, dis, sA, rsA, N);
    scan_blk<<<nb, 1024, 0, stream>>>(deg, off, bsum, N);
    scan_top<<<1, 64, 0, stream>>>(bsum, nb);
    scan_add<<<nb, 1024, 0, stream>>>(off, bsum, N);
    fill_edges<<<(E + TPB - 1) / TPB, TPB, 0, stream>>>(row, col, off, cur, esrc, E);
    conv_all<<<(253952 + TPB - 1) / TPB, TPB, 0, stream>>>(
        lins1, lins2, m1w1, m1w2, m2w1, m2w2, Wc1h, Wc1l, Wc2h, Wc2l, Wm1ah, Wm1al, Wm1bh,
        Wm1bl, Wm2ah, Wm2al, Wm2bh, Wm2bl);
    conv_xg<<<(N * 128 + TPB - 1) / TPB, TPB, 0, stream>>>(x, slab, g0, dis, sA, N * 128);

    unsigned* slabU = (unsigned*)slab;
    unsigned* g0U = (unsigned*)g0;
    const int HG = (N + 63) / 64;
    auto launch_prop = [&](const unsigned* gi, int idl, unsigned* go, int odl) {
        prop<<<2048, 256, 0, stream>>>(gi, idl, go, odl, dis, off, esrc, N);
    };

    // ---- Layer 1: 6 hops into slab cols 1..6 ----
    launch_prop(g0U, 64, slabU + 64, 448);
    for (int k = 2; k <= 6; ++k)
        launch_prop(slabU + (size_t)(k - 1) * 64, 448, slabU + (size_t)k * 64, 448);
    // concat GEMM K=896 -> ACC
    gemm<128, 14, 0><<<dim3(HG, 1), 256, 0, stream>>>(
        N, slab, 896, Wc1h, Wc1l, 896, ACC, 128, rsA, 1, bias1, nullptr, nullptr, nullptr, 0,
        nullptr, nullptr, 0, nullptr);
    // MLP1a: Z = relu(bn(ACC@W+b))  [N,256]
    gemm<128, 2, 0><<<dim3(HG, 2), 256, 0, stream>>>(
        N, ACC, 128, Wm1ah, Wm1al, 128, Z, 256, nullptr, 2, m1b1, bn1g, bn1b, nullptr, 0,
        nullptr, nullptr, 0, nullptr);
    // MLP1b: h1 = relu(Z@W+b); slab col0 = s*h1, g0 = dis*h1
    gemm<128, 4, 0><<<dim3(HG, 1), 256, 0, stream>>>(
        N, Z, 256, Wm1bh, Wm1bl, 256, nullptr, 0, nullptr, 3, m1b2, nullptr, nullptr, slab, 896,
        sA, g0, 128, dis);

    // ---- Layer 2: 6 hops ----
    launch_prop(g0U, 64, slabU + 64, 448);
    for (int k = 2; k <= 6; ++k)
        launch_prop(slabU + (size_t)(k - 1) * 64, 448, slabU + (size_t)k * 64, 448);
    // concat GEMM K=896, Ntot=64 -> ACC2
    gemm<64, 14, 0><<<dim3(HG, 1), 256, 0, stream>>>(
        N, slab, 896, Wc2h, Wc2l, 896, ACC2, 64, rsA, 1, bias2, nullptr, nullptr, nullptr, 0,
        nullptr, nullptr, 0, nullptr);
    // MLP2a: Z2 = relu(bn(ACC2@W+b)) [N,128] (reuse Z)
    gemm<128, 1, 0><<<dim3(HG, 1), 256, 0, stream>>>(
        N, ACC2, 64, Wm2ah, Wm2al, 64, Z, 128, nullptr, 2, m2b1, bn2g, bn2b, nullptr, 0, nullptr,
        nullptr, 0, nullptr);
    // MLP2b: out = Z2@W + b (fp32)
    gemm<64, 2, 1><<<dim3(HG, 1), 256, 0, stream>>>(
        N, Z, 128, Wm2bh, Wm2bl, 128, out, 64, nullptr, 1, m2b2, nullptr, nullptr, nullptr, 0,
        nullptr, nullptr, 0, nullptr);
}